// Round 1
// baseline (75.946 us; speedup 1.0000x reference)
//
#include <hip/hip_runtime.h>

// Householder reflection per row:
//   out = z - 2 * v * (v.z) / (v.v)
// B = 16384 rows, L = 2048 cols, fp32.
// One 256-thread block per row; each thread owns 8 elements (2x float4)
// of v and z, held in registers across the reduce -> write phases so
// v and z are each read from HBM exactly once.

#define ROW_LEN 2048
#define BLOCK 256
#define WAVES (BLOCK / 64)

__global__ __launch_bounds__(BLOCK) void householder_row_kernel(
    const float* __restrict__ v,
    const float* __restrict__ z,
    float* __restrict__ out)
{
    const int row = blockIdx.x;
    const size_t base = (size_t)row * ROW_LEN;
    const int t = threadIdx.x;

    const float4* v4 = reinterpret_cast<const float4*>(v + base);
    const float4* z4 = reinterpret_cast<const float4*>(z + base);
    float4* o4 = reinterpret_cast<float4*>(out + base);

    // 2048 floats = 512 float4; 256 threads -> 2 float4 each, coalesced.
    float4 va = v4[t];
    float4 vb = v4[t + BLOCK];
    float4 za = z4[t];
    float4 zb = z4[t + BLOCK];

    float vz = va.x * za.x + va.y * za.y + va.z * za.z + va.w * za.w
             + vb.x * zb.x + vb.y * zb.y + vb.z * zb.z + vb.w * zb.w;
    float vv = va.x * va.x + va.y * va.y + va.z * va.z + va.w * va.w
             + vb.x * vb.x + vb.y * vb.y + vb.z * vb.z + vb.w * vb.w;

    // Wave-level butterfly reduce across 64 lanes.
    #pragma unroll
    for (int off = 32; off > 0; off >>= 1) {
        vz += __shfl_down(vz, off);
        vv += __shfl_down(vv, off);
    }

    __shared__ float svz[WAVES];
    __shared__ float svv[WAVES];
    __shared__ float s_scale;

    const int wave = t >> 6;
    const int lane = t & 63;
    if (lane == 0) { svz[wave] = vz; svv[wave] = vv; }
    __syncthreads();

    if (t == 0) {
        float tvz = 0.f, tvv = 0.f;
        #pragma unroll
        for (int w = 0; w < WAVES; ++w) { tvz += svz[w]; tvv += svv[w]; }
        s_scale = 2.0f * tvz / tvv;
    }
    __syncthreads();

    const float s = s_scale;

    float4 oa, ob;
    oa.x = za.x - s * va.x;
    oa.y = za.y - s * va.y;
    oa.z = za.z - s * va.z;
    oa.w = za.w - s * va.w;
    ob.x = zb.x - s * vb.x;
    ob.y = zb.y - s * vb.y;
    ob.z = zb.z - s * vb.z;
    ob.w = zb.w - s * vb.w;

    o4[t] = oa;
    o4[t + BLOCK] = ob;
}

extern "C" void kernel_launch(void* const* d_in, const int* in_sizes, int n_in,
                              void* d_out, int out_size, void* d_ws, size_t ws_size,
                              hipStream_t stream) {
    const float* v = (const float*)d_in[0];
    const float* z = (const float*)d_in[1];
    float* out = (float*)d_out;

    const int B = in_sizes[0] / ROW_LEN;  // 16384
    householder_row_kernel<<<B, BLOCK, 0, stream>>>(v, z, out);
}

// Round 3
// 59.874 us; speedup vs baseline: 1.2684x; 1.2684x over previous
//
#include <hip/hip_runtime.h>

// Householder reflection per row:
//   out = z - 2 * v * (v.z) / (v.v)
// B = 16384 rows, L = 2048 cols, fp32.
// One 256-thread block per row; each thread owns 8 elements (2x float4)
// of v and z, held in registers across the reduce -> write phases so
// v and z are each read from HBM exactly once.
//
// R3: use ext_vector float4 (not HIP_vector_type) so
// __builtin_nontemporal_store accepts it. Nontemporal output stores keep
// the write-once stream out of L2/L3 so the 256 MiB of inputs stay
// L3-resident across replays.

#define ROW_LEN 2048
#define BLOCK 256
#define WAVES (BLOCK / 64)

typedef float v4f __attribute__((ext_vector_type(4)));

__global__ __launch_bounds__(BLOCK) void householder_row_kernel(
    const float* __restrict__ v,
    const float* __restrict__ z,
    float* __restrict__ out)
{
    const int row = blockIdx.x;
    const size_t base = (size_t)row * ROW_LEN;
    const int t = threadIdx.x;

    const v4f* v4 = reinterpret_cast<const v4f*>(v + base);
    const v4f* z4 = reinterpret_cast<const v4f*>(z + base);
    v4f* o4 = reinterpret_cast<v4f*>(out + base);

    // 2048 floats = 512 float4; 256 threads -> 2 float4 each, coalesced.
    v4f va = v4[t];
    v4f vb = v4[t + BLOCK];
    v4f za = z4[t];
    v4f zb = z4[t + BLOCK];

    float vz = va.x * za.x + va.y * za.y + va.z * za.z + va.w * za.w
             + vb.x * zb.x + vb.y * zb.y + vb.z * zb.z + vb.w * zb.w;
    float vv = va.x * va.x + va.y * va.y + va.z * va.z + va.w * va.w
             + vb.x * vb.x + vb.y * vb.y + vb.z * vb.z + vb.w * vb.w;

    // Wave-level butterfly reduce across 64 lanes.
    #pragma unroll
    for (int off = 32; off > 0; off >>= 1) {
        vz += __shfl_down(vz, off);
        vv += __shfl_down(vv, off);
    }

    __shared__ float svz[WAVES];
    __shared__ float svv[WAVES];

    const int wave = t >> 6;
    const int lane = t & 63;
    if (lane == 0) { svz[wave] = vz; svv[wave] = vv; }
    __syncthreads();

    // All threads sum the 4 per-wave partials (broadcast reads, no conflict).
    float tvz = 0.f, tvv = 0.f;
    #pragma unroll
    for (int w = 0; w < WAVES; ++w) { tvz += svz[w]; tvv += svv[w]; }
    const float s = 2.0f * tvz / tvv;

    v4f oa = za - s * va;
    v4f ob = zb - s * vb;

    // Nontemporal: don't allocate the write-once output in L2/L3.
    __builtin_nontemporal_store(oa, &o4[t]);
    __builtin_nontemporal_store(ob, &o4[t + BLOCK]);
}

extern "C" void kernel_launch(void* const* d_in, const int* in_sizes, int n_in,
                              void* d_out, int out_size, void* d_ws, size_t ws_size,
                              hipStream_t stream) {
    const float* v = (const float*)d_in[0];
    const float* z = (const float*)d_in[1];
    float* out = (float*)d_out;

    const int B = in_sizes[0] / ROW_LEN;  // 16384
    householder_row_kernel<<<B, BLOCK, 0, stream>>>(v, z, out);
}